// Round 5
// baseline (1833.205 us; speedup 1.0000x reference)
//
#include <hip/hip_runtime.h>
#include <math.h>

// Swin transformer block, fp32 reference-faithful implementation.
// B=4, H=W=128, C=256, HID=1024, HEADS=8, hd=32, WIN=8, SHIFT=4.
//
// Workspace is adaptive on ws_size (host-side branch, deterministic):
//   FULL  (ws >= 3*MC+16K floats ~201.4 MB): 13 launches, buffers full-size.
//   SPLIT (else, needs ~100.7 MB): attention + MLP per batch image, lin2/conv
//          strip-mined; same device kernels, more launches.
// d_out serves as win (LN1 out) then x1 (attn residual out); final GEMM
// does a safe in-place residual read-then-write on d_out.

#define TOK   65536      // B*H*W
#define CDIM  256
#define HIDD  1024
#define PIXB  16384      // pixels per batch image (128*128)

__device__ __forceinline__ float gelu_exact(float v) {
    return 0.5f * v * (1.0f + erff(v * 0.7071067811865476f));
}

// window-layout token t -> spatial row index (b*16384 + h*128 + w),
// including the +SHIFT unroll. Works for batch-local t (b bits zero).
__device__ __forceinline__ int win_row_map(int t) {
    int bw = t >> 6, n = t & 63;
    int b = bw >> 8, widx = bw & 255;
    int wh = widx >> 4, ww = widx & 15;
    int i = n >> 3, j = n & 7;
    int h = (wh * 8 + i + 4) & 127;
    int w = (ww * 8 + j + 4) & 127;
    return (b << 14) | (h << 7) | w;
}

// ---------------- LayerNorm (one wave per token, 4 tokens/block) -----------
template<bool WINDOW>
__global__ __launch_bounds__(256) void ln_kernel(const float* __restrict__ in,
    const float* __restrict__ gw, const float* __restrict__ gb,
    float* __restrict__ out)
{
    int wave = threadIdx.x >> 6;
    int lane = threadIdx.x & 63;
    int t = blockIdx.x * 4 + wave;
    int src = WINDOW ? win_row_map(t) : t;
    const float4 v = *(const float4*)(in + (size_t)src * CDIM + lane * 4);
    float sum = v.x + v.y + v.z + v.w;
    float sq  = v.x * v.x + v.y * v.y + v.z * v.z + v.w * v.w;
#pragma unroll
    for (int off = 32; off > 0; off >>= 1) {
        sum += __shfl_xor(sum, off);
        sq  += __shfl_xor(sq, off);
    }
    float mean = sum * (1.0f / CDIM);
    float var  = sq * (1.0f / CDIM) - mean * mean;
    float rstd = rsqrtf(var + 1e-5f);
    const float4 w4 = *(const float4*)(gw + lane * 4);
    const float4 b4 = *(const float4*)(gb + lane * 4);
    float4 o4;
    o4.x = (v.x - mean) * rstd * w4.x + b4.x;
    o4.y = (v.y - mean) * rstd * w4.y + b4.y;
    o4.z = (v.z - mean) * rstd * w4.z + b4.z;
    o4.w = (v.w - mean) * rstd * w4.w + b4.w;
    *(float4*)(out + (size_t)t * CDIM + lane * 4) = o4;
}

// ---------------- Generic fp32 GEMM, 128x128 tile, 256 threads -------------
// C[M,N] = A[M,K] @ W[K,N] + bias, with epilogue variants.
// 8x8 accumulator per thread; register-prefetch double-buffered staging.
#define EPI_NONE   0
#define EPI_GELU   1
#define EPI_WINRES 2   // out[map(row)] = R[map(row)] + v  (proj)
#define EPI_RES    3   // out[row] = R[row] + v            (lin2; in-place ok)

template<int EPI>
__global__ __launch_bounds__(256) void gemm_kernel(const float* __restrict__ A,
    const float* __restrict__ W, const float* __restrict__ bias,
    float* __restrict__ C, const float* __restrict__ R,
    int M, int N, int K)
{
    __shared__ float As[16][128];   // [k][m]
    __shared__ float Bs[16][128];   // [k][n]
    int tid = threadIdx.x;
    int tx = tid & 15, ty = tid >> 4;
    int bm = blockIdx.y << 7, bn = blockIdx.x << 7;

    float acc[2][2][4][4] = {};

    int ar = tid >> 1, ac = (tid & 1) << 3;      // A tile: 128 rows x 16 cols
    int br = tid >> 4, bc = (tid & 15) << 3;     // B tile: 16 rows x 128 cols
    const float* Aptr = A + (size_t)(bm + ar) * K + ac;
    const float* Wptr = W + (size_t)br * N + bn + bc;

    // preload k0 = 0 tile into registers
    float4 av0 = *(const float4*)(Aptr);
    float4 av1 = *(const float4*)(Aptr + 4);
    float4 bv0 = *(const float4*)(Wptr);
    float4 bv1 = *(const float4*)(Wptr + 4);

    for (int k0 = 0; k0 < K; k0 += 16) {
        As[ac + 0][ar] = av0.x;
        As[ac + 1][ar] = av0.y;
        As[ac + 2][ar] = av0.z;
        As[ac + 3][ar] = av0.w;
        As[ac + 4][ar] = av1.x;
        As[ac + 5][ar] = av1.y;
        As[ac + 6][ar] = av1.z;
        As[ac + 7][ar] = av1.w;
        *(float4*)(&Bs[br][bc]) = bv0;
        *(float4*)(&Bs[br][bc + 4]) = bv1;
        __syncthreads();
        if (k0 + 16 < K) {   // wave-uniform; prefetch next tile during compute
            av0 = *(const float4*)(Aptr + k0 + 16);
            av1 = *(const float4*)(Aptr + k0 + 20);
            bv0 = *(const float4*)(Wptr + (size_t)(k0 + 16) * N);
            bv1 = *(const float4*)(Wptr + (size_t)(k0 + 16) * N + 4);
        }
#pragma unroll
        for (int k = 0; k < 16; ++k) {
            float4 a[2], b[2];
            a[0] = *(const float4*)(&As[k][ty << 2]);
            a[1] = *(const float4*)(&As[k][(ty << 2) + 64]);
            b[0] = *(const float4*)(&Bs[k][tx << 2]);
            b[1] = *(const float4*)(&Bs[k][(tx << 2) + 64]);
#pragma unroll
            for (int ii = 0; ii < 2; ++ii) {
                const float4 av = a[ii];
#pragma unroll
                for (int jj = 0; jj < 2; ++jj) {
                    const float4 bv = b[jj];
                    float* p = &acc[ii][jj][0][0];
                    p[0]  = fmaf(av.x, bv.x, p[0]);
                    p[1]  = fmaf(av.x, bv.y, p[1]);
                    p[2]  = fmaf(av.x, bv.z, p[2]);
                    p[3]  = fmaf(av.x, bv.w, p[3]);
                    p[4]  = fmaf(av.y, bv.x, p[4]);
                    p[5]  = fmaf(av.y, bv.y, p[5]);
                    p[6]  = fmaf(av.y, bv.z, p[6]);
                    p[7]  = fmaf(av.y, bv.w, p[7]);
                    p[8]  = fmaf(av.z, bv.x, p[8]);
                    p[9]  = fmaf(av.z, bv.y, p[9]);
                    p[10] = fmaf(av.z, bv.z, p[10]);
                    p[11] = fmaf(av.z, bv.w, p[11]);
                    p[12] = fmaf(av.w, bv.x, p[12]);
                    p[13] = fmaf(av.w, bv.y, p[13]);
                    p[14] = fmaf(av.w, bv.z, p[14]);
                    p[15] = fmaf(av.w, bv.w, p[15]);
                }
            }
        }
        __syncthreads();
    }

#pragma unroll
    for (int jj = 0; jj < 2; ++jj) {
        int col = bn + (tx << 2) + jj * 64;
        float4 bias4 = *(const float4*)(bias + col);
#pragma unroll
        for (int ii = 0; ii < 2; ++ii) {
#pragma unroll
            for (int i = 0; i < 4; ++i) {
                int row = bm + (ty << 2) + ii * 64 + i;
                int drow = (EPI == EPI_WINRES) ? win_row_map(row) : row;
                float v0 = acc[ii][jj][i][0] + bias4.x;
                float v1 = acc[ii][jj][i][1] + bias4.y;
                float v2 = acc[ii][jj][i][2] + bias4.z;
                float v3 = acc[ii][jj][i][3] + bias4.w;
                if (EPI == EPI_GELU) {
                    v0 = gelu_exact(v0); v1 = gelu_exact(v1);
                    v2 = gelu_exact(v2); v3 = gelu_exact(v3);
                }
                if (EPI == EPI_WINRES || EPI == EPI_RES) {
                    float4 r4 = *(const float4*)(R + (size_t)drow * N + col);
                    v0 += r4.x; v1 += r4.y; v2 += r4.z; v3 += r4.w;
                }
                *(float4*)(C + (size_t)drow * N + col) =
                    make_float4(v0, v1, v2, v3);
            }
        }
    }
}

// ---------------- Windowed attention: one wave per (window, head) ----------
// Works on any contiguous whole number of batch images: window mask index
// widx = bw & 255 is batch-local-invariant. Writes o in-place over q.
__global__ __launch_bounds__(64) void attn_kernel(float* __restrict__ q,
    const float* __restrict__ kv, const float* __restrict__ rpb)
{
    __shared__ float kS[64][32];
    __shared__ float vS[64][32];
    int blk = blockIdx.x;
    int bw = blk >> 3, head = blk & 7;
    int lane = threadIdx.x;

    size_t kvrow = ((size_t)(bw * 64 + lane)) * 512 + head * 32;
#pragma unroll
    for (int d0 = 0; d0 < 8; ++d0) {
        *(float4*)(&kS[lane][d0 * 4]) = *(const float4*)(kv + kvrow + d0 * 4);
        *(float4*)(&vS[lane][d0 * 4]) = *(const float4*)(kv + kvrow + 256 + d0 * 4);
    }
    float4 qr[8];
    size_t qrow = ((size_t)(bw * 64 + lane)) * 256 + head * 32;
#pragma unroll
    for (int d0 = 0; d0 < 8; ++d0)
        qr[d0] = *(const float4*)(q + qrow + d0 * 4);
    __syncthreads();

    int widx = bw & 255;
    int wh = widx >> 4, ww = widx & 15;
    int i1 = lane >> 3, j1 = lane & 7;
    int h1 = wh * 8 + i1, w1 = ww * 8 + j1;
    int lbl1 = (h1 < 120 ? 0 : (h1 < 124 ? 1 : 2)) * 3
             + (w1 < 120 ? 0 : (w1 < 124 ? 1 : 2));
    const float scale = 0.17677669529663687f;  // 32^-0.5

    float s[64];
    float mx = -1e30f;
#pragma unroll
    for (int m = 0; m < 64; ++m) {
        float a = 0.f;
#pragma unroll
        for (int d0 = 0; d0 < 8; ++d0) {
            float4 kk = *(const float4*)(&kS[m][d0 * 4]);
            a = fmaf(qr[d0].x, kk.x, a);
            a = fmaf(qr[d0].y, kk.y, a);
            a = fmaf(qr[d0].z, kk.z, a);
            a = fmaf(qr[d0].w, kk.w, a);
        }
        int i2 = m >> 3, j2 = m & 7;
        int idx = (i1 - i2 + 7) * 15 + (j1 - j2 + 7);
        float b = rpb[idx * 8 + head];
        int h2 = wh * 8 + i2, w2 = ww * 8 + j2;
        int lbl2 = (h2 < 120 ? 0 : (h2 < 124 ? 1 : 2)) * 3
                 + (w2 < 120 ? 0 : (w2 < 124 ? 1 : 2));
        float sv = a * scale + b + ((lbl1 != lbl2) ? -100.f : 0.f);
        s[m] = sv;
        mx = fmaxf(mx, sv);
    }
    float sum = 0.f;
#pragma unroll
    for (int m = 0; m < 64; ++m) {
        float e = __expf(s[m] - mx);
        s[m] = e;
        sum += e;
    }
    float inv = 1.0f / sum;

    float oa[32];
#pragma unroll
    for (int d = 0; d < 32; ++d) oa[d] = 0.f;
#pragma unroll
    for (int m = 0; m < 64; ++m) {
        float p = s[m];
#pragma unroll
        for (int d0 = 0; d0 < 8; ++d0) {
            float4 vv = *(const float4*)(&vS[m][d0 * 4]);
            oa[d0 * 4 + 0] = fmaf(p, vv.x, oa[d0 * 4 + 0]);
            oa[d0 * 4 + 1] = fmaf(p, vv.y, oa[d0 * 4 + 1]);
            oa[d0 * 4 + 2] = fmaf(p, vv.z, oa[d0 * 4 + 2]);
            oa[d0 * 4 + 3] = fmaf(p, vv.w, oa[d0 * 4 + 3]);
        }
    }
#pragma unroll
    for (int d0 = 0; d0 < 8; ++d0) {
        float4 ov = make_float4(oa[d0 * 4 + 0] * inv, oa[d0 * 4 + 1] * inv,
                                oa[d0 * 4 + 2] * inv, oa[d0 * 4 + 3] * inv);
        *(float4*)(q + qrow + d0 * 4) = ov;   // in-place over q
    }
}

// ---------------- depthwise-conv weight transpose: [HID,3,3]->[9][HID] -----
__global__ __launch_bounds__(256) void prep_dw_kernel(const float* __restrict__ dww,
    float* __restrict__ wT)
{
    int gid = blockIdx.x * 256 + threadIdx.x;
    if (gid >= 9 * HIDD) return;
    int k = gid >> 10, c = gid & 1023;
    wT[gid] = dww[c * 9 + k];
}

// ---- depthwise 3x3 conv + bias + GELU, row strip [y0, y0+rows) of one -----
// batch image. h = full-image input (halo reads stay in-bounds via clamps);
// out = strip-local output. Grid covers rows*128 pixels.
__global__ __launch_bounds__(256) void dwconv_kernel(const float* __restrict__ h,
    const float* __restrict__ wT, const float* __restrict__ db,
    float* __restrict__ out, int y0)
{
    int gid = blockIdx.x * 256 + threadIdx.x;
    int c = (gid & 255) << 2;                   // channel (x4)
    int pix = gid >> 8;                         // strip-local pixel
    int x = pix & 127, y = y0 + (pix >> 7);     // global image coords

    float4 acc = *(const float4*)(db + c);
#pragma unroll
    for (int ky = 0; ky < 3; ++ky) {
        int yy = y + ky - 1;
        if (yy < 0 || yy > 127) continue;
#pragma unroll
        for (int kx = 0; kx < 3; ++kx) {
            int xx = x + kx - 1;
            if (xx < 0 || xx > 127) continue;
            float4 iv = *(const float4*)(h + ((size_t)((yy << 7) | xx) << 10) + c);
            float4 wv = *(const float4*)(wT + (ky * 3 + kx) * HIDD + c);
            acc.x = fmaf(iv.x, wv.x, acc.x);
            acc.y = fmaf(iv.y, wv.y, acc.y);
            acc.z = fmaf(iv.z, wv.z, acc.z);
            acc.w = fmaf(iv.w, wv.w, acc.w);
        }
    }
    float4 o4 = make_float4(gelu_exact(acc.x), gelu_exact(acc.y),
                            gelu_exact(acc.z), gelu_exact(acc.w));
    *(float4*)(out + ((size_t)pix << 10) + c) = o4;
}

// ---------------------------------------------------------------------------
extern "C" void kernel_launch(void* const* d_in, const int* in_sizes, int n_in,
                              void* d_out, int out_size, void* d_ws, size_t ws_size,
                              hipStream_t stream) {
    const float* x    = (const float*)d_in[0];
    const float* n1w  = (const float*)d_in[3];
    const float* n1b  = (const float*)d_in[4];
    const float* wq   = (const float*)d_in[5];
    const float* bq   = (const float*)d_in[6];
    const float* wkv  = (const float*)d_in[7];
    const float* bkv  = (const float*)d_in[8];
    const float* rpb  = (const float*)d_in[9];
    const float* pw   = (const float*)d_in[10];
    const float* pb   = (const float*)d_in[11];
    const float* n2w  = (const float*)d_in[12];
    const float* n2b  = (const float*)d_in[13];
    const float* l1w  = (const float*)d_in[14];
    const float* l1b  = (const float*)d_in[15];
    const float* dww  = (const float*)d_in[16];
    const float* dwb  = (const float*)d_in[17];
    const float* l2w  = (const float*)d_in[18];
    const float* l2b  = (const float*)d_in[19];
    float* out = (float*)d_out;
    float* ws  = (float*)d_ws;

    const size_t MC = (size_t)TOK * CDIM;   // 16,777,216 floats
    const size_t BC = (size_t)PIXB * CDIM;  // 4,194,304 floats per batch image
    float* wT   = ws;                       // [0, 9216) transposed dw weights
    float* base = ws + 16384;               // big buffers start here
    float* win  = out;                      // d_out: win, then x1
    float* x1   = out;

    const bool full = ws_size >= (3 * MC + 16384) * sizeof(float);

    // 1. LN1 + roll + window partition (win lives in d_out) — both paths
    ln_kernel<true><<<TOK / 4, 256, 0, stream>>>(x, n1w, n1b, win);
    // depthwise conv weight transpose — both paths
    prep_dw_kernel<<<(9 * HIDD + 255) / 256, 256, 0, stream>>>(dww, wT);

    if (full) {
        float* qb  = base;                  // [0,1MC): q, then o, then x2
        float* x2  = base;
        float* kvb = base + MC;             // [1MC,3MC): kv; later hb/hc
        float* hbB = base + MC;
        float* hcB = base + 2 * MC;

        gemm_kernel<EPI_NONE><<<dim3(CDIM / 128, TOK / 128), 256, 0, stream>>>(
            win, wq, bq, qb, nullptr, TOK, CDIM, CDIM);
        gemm_kernel<EPI_NONE><<<dim3(2 * CDIM / 128, TOK / 128), 256, 0, stream>>>(
            win, wkv, bkv, kvb, nullptr, TOK, 2 * CDIM, CDIM);
        attn_kernel<<<(TOK / 64) * 8, 64, 0, stream>>>(qb, kvb, rpb);
        gemm_kernel<EPI_WINRES><<<dim3(CDIM / 128, TOK / 128), 256, 0, stream>>>(
            qb, pw, pb, x1, x, TOK, CDIM, CDIM);
        ln_kernel<false><<<TOK / 4, 256, 0, stream>>>(x1, n2w, n2b, x2);
        for (int b = 0; b < 4; ++b) {
            const float* x2b = x2 + (size_t)b * BC;
            const float* x1b = x1 + (size_t)b * BC;
            float* outb = out + (size_t)b * BC;
            gemm_kernel<EPI_GELU><<<dim3(HIDD / 128, PIXB / 128), 256, 0, stream>>>(
                x2b, l1w, l1b, hbB, nullptr, PIXB, HIDD, CDIM);
            dwconv_kernel<<<PIXB * (HIDD / 4) / 256, 256, 0, stream>>>(
                hbB, wT, dwb, hcB, 0);
            gemm_kernel<EPI_RES><<<dim3(CDIM / 128, PIXB / 128), 256, 0, stream>>>(
                hcB, l2w, l2b, outb, x1b, PIXB, CDIM, HIDD);
        }
    } else {
        // SPLIT path: peak 1.5*MC + 16K floats (~100.7 MB).
        // Attention per batch image: q 0.25MC @0, kv 0.5MC @0.25MC.
        float* qb_s  = base;
        float* kvb_s = base + MC / 4;
        for (int b = 0; b < 4; ++b) {
            const float* winb = win + (size_t)b * BC;
            const float* xb   = x   + (size_t)b * BC;
            float* x1b = x1 + (size_t)b * BC;
            gemm_kernel<EPI_NONE><<<dim3(CDIM / 128, PIXB / 128), 256, 0, stream>>>(
                winb, wq, bq, qb_s, nullptr, PIXB, CDIM, CDIM);
            gemm_kernel<EPI_NONE><<<dim3(2 * CDIM / 128, PIXB / 128), 256, 0, stream>>>(
                winb, wkv, bkv, kvb_s, nullptr, PIXB, 2 * CDIM, CDIM);
            attn_kernel<<<(PIXB / 64) * 8, 64, 0, stream>>>(qb_s, kvb_s, rpb);
            gemm_kernel<EPI_WINRES><<<dim3(CDIM / 128, PIXB / 128), 256, 0, stream>>>(
                qb_s, pw, pb, x1b, xb, PIXB, CDIM, CDIM);
        }
        // MLP per batch: x2 0.25MC @0, hb 1MC @0.25MC, hc strip 0.25MC @1.25MC.
        float* x2_s = base;
        float* hb_s = base + MC / 4;
        float* hc_s = base + MC / 4 + MC;
        const int SROWS = 32, SPIX = SROWS * 128;   // 4096 pixels per strip
        for (int b = 0; b < 4; ++b) {
            const float* x1b = x1 + (size_t)b * BC;
            float* outb = out + (size_t)b * BC;
            ln_kernel<false><<<PIXB / 4, 256, 0, stream>>>(x1b, n2w, n2b, x2_s);
            gemm_kernel<EPI_GELU><<<dim3(HIDD / 128, PIXB / 128), 256, 0, stream>>>(
                x2_s, l1w, l1b, hb_s, nullptr, PIXB, HIDD, CDIM);
            for (int s = 0; s < 4; ++s) {
                dwconv_kernel<<<SPIX * (HIDD / 4) / 256, 256, 0, stream>>>(
                    hb_s, wT, dwb, hc_s, s * SROWS);
                gemm_kernel<EPI_RES><<<dim3(CDIM / 128, SPIX / 128), 256, 0, stream>>>(
                    hc_s, l2w, l2b, outb + (size_t)s * SPIX * CDIM,
                    x1b + (size_t)s * SPIX * CDIM, SPIX, CDIM, HIDD);
            }
        }
    }
}

// Round 6
// 1159.320 us; speedup vs baseline: 1.5813x; 1.5813x over previous
//
#include <hip/hip_runtime.h>
#include <math.h>

// Swin transformer block. fp32 everywhere except GEMMs, which run on MFMA
// with 2-term bf16 splits (Ah*Bh + Ah*Bl + Al*Bh) — ~2^-18 relative error.
// B=4, H=W=128, C=256, HID=1024, HEADS=8, hd=32, WIN=8, SHIFT=4.
//
// Workspace: [0,9216) dw-weight transpose | [16384, +393216) WT_hi (bf16)
// | next 393216 floats WT_lo | big buffers at ws+1048576 floats.
// FULL path needs 1048576 + 3*MC floats (~205.5 MB); SPLIT ~105 MB.

#define TOK   65536      // B*H*W
#define CDIM  256
#define HIDD  1024
#define PIXB  16384      // pixels per batch image

typedef __attribute__((ext_vector_type(8))) short bf16x8;
typedef __attribute__((ext_vector_type(4))) float f32x4;

__device__ __forceinline__ float gelu_exact(float v) {
    return 0.5f * v * (1.0f + erff(v * 0.7071067811865476f));
}

__device__ __forceinline__ unsigned short bf16_rne(float f) {
    unsigned u = __float_as_uint(f);
    unsigned r = u + 0x7fffu + ((u >> 16) & 1u);
    return (unsigned short)(r >> 16);
}

// window-layout token t -> spatial row (b*16384 + h*128 + w), incl. unshift.
__device__ __forceinline__ int win_row_map(int t) {
    int bw = t >> 6, n = t & 63;
    int b = bw >> 8, widx = bw & 255;
    int wh = widx >> 4, ww = widx & 15;
    int i = n >> 3, j = n & 7;
    int h = (wh * 8 + i + 4) & 127;
    int w = (ww * 8 + j + 4) & 127;
    return (b << 14) | (h << 7) | w;
}

// ---------------- LayerNorm (one wave per token, 4 tokens/block) -----------
template<bool WINDOW>
__global__ __launch_bounds__(256) void ln_kernel(const float* __restrict__ in,
    const float* __restrict__ gw, const float* __restrict__ gb,
    float* __restrict__ out)
{
    int wave = threadIdx.x >> 6;
    int lane = threadIdx.x & 63;
    int t = blockIdx.x * 4 + wave;
    int src = WINDOW ? win_row_map(t) : t;
    const float4 v = *(const float4*)(in + (size_t)src * CDIM + lane * 4);
    float sum = v.x + v.y + v.z + v.w;
    float sq  = v.x * v.x + v.y * v.y + v.z * v.z + v.w * v.w;
#pragma unroll
    for (int off = 32; off > 0; off >>= 1) {
        sum += __shfl_xor(sum, off);
        sq  += __shfl_xor(sq, off);
    }
    float mean = sum * (1.0f / CDIM);
    float var  = sq * (1.0f / CDIM) - mean * mean;
    float rstd = rsqrtf(var + 1e-5f);
    const float4 w4 = *(const float4*)(gw + lane * 4);
    const float4 b4 = *(const float4*)(gb + lane * 4);
    float4 o4;
    o4.x = (v.x - mean) * rstd * w4.x + b4.x;
    o4.y = (v.y - mean) * rstd * w4.y + b4.y;
    o4.z = (v.z - mean) * rstd * w4.z + b4.z;
    o4.w = (v.w - mean) * rstd * w4.w + b4.w;
    *(float4*)(out + (size_t)t * CDIM + lane * 4) = o4;
}

// ------- weight prep: W[K][N] fp32 -> hi/lo bf16 in [N][K] layout ----------
__global__ __launch_bounds__(256) void wprep_kernel(const float* __restrict__ W,
    short* __restrict__ hi, short* __restrict__ lo, int K, int N)
{
    int idx = blockIdx.x * 256 + threadIdx.x;
    if (idx >= K * N) return;
    int k = idx / N, n = idx - k * N;
    float f = W[idx];
    unsigned short h = bf16_rne(f);
    float fh = __uint_as_float((unsigned)h << 16);
    unsigned short l = bf16_rne(f - fh);
    hi[(size_t)n * K + k] = (short)h;
    lo[(size_t)n * K + k] = (short)l;
}

// ---------------- MFMA GEMM, 128x128 tile, 256 threads (4 waves 2x2) -------
// C[M,N] = A[M,K] (fp32, split on the fly) @ WT (pre-split bf16 [N][K]).
// Per wave: 64x64 output = 4x4 frags of 16x16; 48 MFMA / 16 ds_read_b128
// per K-step of 32. LDS rows padded to 40 bf16 (80 B) -> ~2-way conflicts.
#define EPI_NONE   0
#define EPI_GELU   1
#define EPI_WINRES 2   // out[map(row)] = R[map(row)] + v  (proj)
#define EPI_RES    3   // out[row] = R[row] + v            (lin2; in-place ok)

template<int EPI>
__global__ __launch_bounds__(256) void mgemm_kernel(const float* __restrict__ A,
    const short* __restrict__ BTh, const short* __restrict__ BTl,
    const float* __restrict__ bias, float* __restrict__ C,
    const float* __restrict__ R, int M, int N, int K)
{
    __shared__ short lds[4 * 5120];
    short* Ah = lds;
    short* Al = lds + 5120;
    short* Bh = lds + 10240;
    short* Bl = lds + 15360;

    const int tid = threadIdx.x;
    const int bm = blockIdx.y << 7, bn = blockIdx.x << 7;
    const int sr = tid >> 1;            // staging row (0..127)
    const int sc = (tid & 1) << 4;      // staging k offset (0/16)

    const float* Aptr = A + (size_t)(bm + sr) * K + sc;
    const short* BhP = BTh + (size_t)(bn + sr) * K + sc;
    const short* BlP = BTl + (size_t)(bn + sr) * K + sc;

    const int wid = tid >> 6, lane = tid & 63;
    const int wr = wid >> 1, wc = wid & 1;
    const int lr = lane & 15, lkq = lane >> 4;
    const int lk = lkq << 3;

    f32x4 acc[4][4] = {};

    for (int k0 = 0; k0 < K; k0 += 32) {
        float va[16];
#pragma unroll
        for (int j = 0; j < 4; ++j) {
            float4 t = *(const float4*)(Aptr + k0 + 4 * j);
            va[4*j+0] = t.x; va[4*j+1] = t.y; va[4*j+2] = t.z; va[4*j+3] = t.w;
        }
        bf16x8 gb0 = *(const bf16x8*)(BhP + k0);
        bf16x8 gb1 = *(const bf16x8*)(BhP + k0 + 8);
        bf16x8 gc0 = *(const bf16x8*)(BlP + k0);
        bf16x8 gc1 = *(const bf16x8*)(BlP + k0 + 8);
        bf16x8 ah0, ah1, al0, al1;
#pragma unroll
        for (int j = 0; j < 8; ++j) {
            unsigned short h0 = bf16_rne(va[j]);
            ah0[j] = (short)h0;
            al0[j] = (short)bf16_rne(va[j] - __uint_as_float((unsigned)h0 << 16));
            unsigned short h1 = bf16_rne(va[j + 8]);
            ah1[j] = (short)h1;
            al1[j] = (short)bf16_rne(va[j + 8] - __uint_as_float((unsigned)h1 << 16));
        }
        __syncthreads();   // previous iteration's LDS reads complete
        *(bf16x8*)&Ah[sr * 40 + sc]     = ah0;
        *(bf16x8*)&Ah[sr * 40 + sc + 8] = ah1;
        *(bf16x8*)&Al[sr * 40 + sc]     = al0;
        *(bf16x8*)&Al[sr * 40 + sc + 8] = al1;
        *(bf16x8*)&Bh[sr * 40 + sc]     = gb0;
        *(bf16x8*)&Bh[sr * 40 + sc + 8] = gb1;
        *(bf16x8*)&Bl[sr * 40 + sc]     = gc0;
        *(bf16x8*)&Bl[sr * 40 + sc + 8] = gc1;
        __syncthreads();   // tile ready

        bf16x8 fah[4], fal[4], fbh[4], fbl[4];
#pragma unroll
        for (int mi = 0; mi < 4; ++mi) {
            int off = (wr * 64 + mi * 16 + lr) * 40 + lk;
            fah[mi] = *(const bf16x8*)&Ah[off];
            fal[mi] = *(const bf16x8*)&Al[off];
        }
#pragma unroll
        for (int ni = 0; ni < 4; ++ni) {
            int off = (wc * 64 + ni * 16 + lr) * 40 + lk;
            fbh[ni] = *(const bf16x8*)&Bh[off];
            fbl[ni] = *(const bf16x8*)&Bl[off];
        }
#pragma unroll
        for (int mi = 0; mi < 4; ++mi)
#pragma unroll
            for (int ni = 0; ni < 4; ++ni) {
                acc[mi][ni] = __builtin_amdgcn_mfma_f32_16x16x32_bf16(
                    fah[mi], fbh[ni], acc[mi][ni], 0, 0, 0);
                acc[mi][ni] = __builtin_amdgcn_mfma_f32_16x16x32_bf16(
                    fah[mi], fbl[ni], acc[mi][ni], 0, 0, 0);
                acc[mi][ni] = __builtin_amdgcn_mfma_f32_16x16x32_bf16(
                    fal[mi], fbh[ni], acc[mi][ni], 0, 0, 0);
            }
    }

    // epilogue: D frag mapping col = lane&15, row = (lane>>4)*4 + reg
#pragma unroll
    for (int mi = 0; mi < 4; ++mi) {
#pragma unroll
        for (int ni = 0; ni < 4; ++ni) {
            int col = bn + wc * 64 + ni * 16 + lr;
            float bv = bias[col];
#pragma unroll
            for (int r = 0; r < 4; ++r) {
                int row = bm + wr * 64 + mi * 16 + lkq * 4 + r;
                float v = acc[mi][ni][r] + bv;
                if (EPI == EPI_GELU) v = gelu_exact(v);
                int drow = (EPI == EPI_WINRES) ? win_row_map(row) : row;
                if (EPI == EPI_WINRES || EPI == EPI_RES)
                    v += R[(size_t)drow * N + col];
                C[(size_t)drow * N + col] = v;
            }
        }
    }
}

// ---------------- Windowed attention: one wave per (window, head) ----------
__global__ __launch_bounds__(64) void attn_kernel(float* __restrict__ q,
    const float* __restrict__ kv, const float* __restrict__ rpb)
{
    __shared__ float kS[64][32];
    __shared__ float vS[64][32];
    int blk = blockIdx.x;
    int bw = blk >> 3, head = blk & 7;
    int lane = threadIdx.x;

    size_t kvrow = ((size_t)(bw * 64 + lane)) * 512 + head * 32;
#pragma unroll
    for (int d0 = 0; d0 < 8; ++d0) {
        *(float4*)(&kS[lane][d0 * 4]) = *(const float4*)(kv + kvrow + d0 * 4);
        *(float4*)(&vS[lane][d0 * 4]) = *(const float4*)(kv + kvrow + 256 + d0 * 4);
    }
    float4 qr[8];
    size_t qrow = ((size_t)(bw * 64 + lane)) * 256 + head * 32;
#pragma unroll
    for (int d0 = 0; d0 < 8; ++d0)
        qr[d0] = *(const float4*)(q + qrow + d0 * 4);
    __syncthreads();

    int widx = bw & 255;
    int wh = widx >> 4, ww = widx & 15;
    int i1 = lane >> 3, j1 = lane & 7;
    int h1 = wh * 8 + i1, w1 = ww * 8 + j1;
    int lbl1 = (h1 < 120 ? 0 : (h1 < 124 ? 1 : 2)) * 3
             + (w1 < 120 ? 0 : (w1 < 124 ? 1 : 2));
    const float scale = 0.17677669529663687f;  // 32^-0.5

    float s[64];
    float mx = -1e30f;
#pragma unroll
    for (int m = 0; m < 64; ++m) {
        float a = 0.f;
#pragma unroll
        for (int d0 = 0; d0 < 8; ++d0) {
            float4 kk = *(const float4*)(&kS[m][d0 * 4]);
            a = fmaf(qr[d0].x, kk.x, a);
            a = fmaf(qr[d0].y, kk.y, a);
            a = fmaf(qr[d0].z, kk.z, a);
            a = fmaf(qr[d0].w, kk.w, a);
        }
        int i2 = m >> 3, j2 = m & 7;
        int idx = (i1 - i2 + 7) * 15 + (j1 - j2 + 7);
        float b = rpb[idx * 8 + head];
        int h2 = wh * 8 + i2, w2 = ww * 8 + j2;
        int lbl2 = (h2 < 120 ? 0 : (h2 < 124 ? 1 : 2)) * 3
                 + (w2 < 120 ? 0 : (w2 < 124 ? 1 : 2));
        float sv = a * scale + b + ((lbl1 != lbl2) ? -100.f : 0.f);
        s[m] = sv;
        mx = fmaxf(mx, sv);
    }
    float sum = 0.f;
#pragma unroll
    for (int m = 0; m < 64; ++m) {
        float e = __expf(s[m] - mx);
        s[m] = e;
        sum += e;
    }
    float inv = 1.0f / sum;

    float oa[32];
#pragma unroll
    for (int d = 0; d < 32; ++d) oa[d] = 0.f;
#pragma unroll
    for (int m = 0; m < 64; ++m) {
        float p = s[m];
#pragma unroll
        for (int d0 = 0; d0 < 8; ++d0) {
            float4 vv = *(const float4*)(&vS[m][d0 * 4]);
            oa[d0 * 4 + 0] = fmaf(p, vv.x, oa[d0 * 4 + 0]);
            oa[d0 * 4 + 1] = fmaf(p, vv.y, oa[d0 * 4 + 1]);
            oa[d0 * 4 + 2] = fmaf(p, vv.z, oa[d0 * 4 + 2]);
            oa[d0 * 4 + 3] = fmaf(p, vv.w, oa[d0 * 4 + 3]);
        }
    }
#pragma unroll
    for (int d0 = 0; d0 < 8; ++d0) {
        float4 ov = make_float4(oa[d0 * 4 + 0] * inv, oa[d0 * 4 + 1] * inv,
                                oa[d0 * 4 + 2] * inv, oa[d0 * 4 + 3] * inv);
        *(float4*)(q + qrow + d0 * 4) = ov;   // in-place over q
    }
}

// ---------------- depthwise-conv weight transpose: [HID,3,3]->[9][HID] -----
__global__ __launch_bounds__(256) void prep_dw_kernel(const float* __restrict__ dww,
    float* __restrict__ wT)
{
    int gid = blockIdx.x * 256 + threadIdx.x;
    if (gid >= 9 * HIDD) return;
    int k = gid >> 10, c = gid & 1023;
    wT[gid] = dww[c * 9 + k];
}

// ---- depthwise 3x3 conv + bias + GELU on row strip [y0, y0+rows) ----------
__global__ __launch_bounds__(256) void dwconv_kernel(const float* __restrict__ h,
    const float* __restrict__ wT, const float* __restrict__ db,
    float* __restrict__ out, int y0)
{
    int gid = blockIdx.x * 256 + threadIdx.x;
    int c = (gid & 255) << 2;                   // channel (x4)
    int pix = gid >> 8;                         // strip-local pixel
    int x = pix & 127, y = y0 + (pix >> 7);

    float4 acc = *(const float4*)(db + c);
#pragma unroll
    for (int ky = 0; ky < 3; ++ky) {
        int yy = y + ky - 1;
        if (yy < 0 || yy > 127) continue;
#pragma unroll
        for (int kx = 0; kx < 3; ++kx) {
            int xx = x + kx - 1;
            if (xx < 0 || xx > 127) continue;
            float4 iv = *(const float4*)(h + ((size_t)((yy << 7) | xx) << 10) + c);
            float4 wv = *(const float4*)(wT + (ky * 3 + kx) * HIDD + c);
            acc.x = fmaf(iv.x, wv.x, acc.x);
            acc.y = fmaf(iv.y, wv.y, acc.y);
            acc.z = fmaf(iv.z, wv.z, acc.z);
            acc.w = fmaf(iv.w, wv.w, acc.w);
        }
    }
    float4 o4 = make_float4(gelu_exact(acc.x), gelu_exact(acc.y),
                            gelu_exact(acc.z), gelu_exact(acc.w));
    *(float4*)(out + ((size_t)pix << 10) + c) = o4;
}

// ---------------------------------------------------------------------------
extern "C" void kernel_launch(void* const* d_in, const int* in_sizes, int n_in,
                              void* d_out, int out_size, void* d_ws, size_t ws_size,
                              hipStream_t stream) {
    const float* x    = (const float*)d_in[0];
    const float* n1w  = (const float*)d_in[3];
    const float* n1b  = (const float*)d_in[4];
    const float* wq   = (const float*)d_in[5];
    const float* bq   = (const float*)d_in[6];
    const float* wkv  = (const float*)d_in[7];
    const float* bkv  = (const float*)d_in[8];
    const float* rpb  = (const float*)d_in[9];
    const float* pw   = (const float*)d_in[10];
    const float* pb   = (const float*)d_in[11];
    const float* n2w  = (const float*)d_in[12];
    const float* n2b  = (const float*)d_in[13];
    const float* l1w  = (const float*)d_in[14];
    const float* l1b  = (const float*)d_in[15];
    const float* dww  = (const float*)d_in[16];
    const float* dwb  = (const float*)d_in[17];
    const float* l2w  = (const float*)d_in[18];
    const float* l2b  = (const float*)d_in[19];
    float* out = (float*)d_out;
    float* ws  = (float*)d_ws;

    const size_t MC = (size_t)TOK * CDIM;   // 16,777,216 floats
    const size_t BC = (size_t)PIXB * CDIM;  // 4,194,304 floats per batch image
    float* wT    = ws;                      // [0, 9216)
    short* WThi  = (short*)(ws + 16384);    // 786432 bf16
    short* WTlo  = (short*)(ws + 16384 + 393216);
    float* base  = ws + 1048576;            // big buffers
    float* win   = out;                     // d_out: win, then x1
    float* x1    = out;

    // weight-split offsets (shorts): [wq, wkv, pw, l1w, l2w]
    const size_t OQ = 0, OKV = 65536, OP = 196608, OL1 = 262144, OL2 = 524288;

    const bool full = ws_size >= (1048576 + 3 * MC) * sizeof(float);

    // prep: LN1 (win in d_out), dw-weight transpose, GEMM weight splits
    ln_kernel<true><<<TOK / 4, 256, 0, stream>>>(x, n1w, n1b, win);
    prep_dw_kernel<<<(9 * HIDD + 255) / 256, 256, 0, stream>>>(dww, wT);
    wprep_kernel<<<(256 * 256 + 255) / 256, 256, 0, stream>>>(wq,  WThi + OQ,  WTlo + OQ,  256, 256);
    wprep_kernel<<<(256 * 512 + 255) / 256, 256, 0, stream>>>(wkv, WThi + OKV, WTlo + OKV, 256, 512);
    wprep_kernel<<<(256 * 256 + 255) / 256, 256, 0, stream>>>(pw,  WThi + OP,  WTlo + OP,  256, 256);
    wprep_kernel<<<(256 * 1024 + 255) / 256, 256, 0, stream>>>(l1w, WThi + OL1, WTlo + OL1, 256, 1024);
    wprep_kernel<<<(1024 * 256 + 255) / 256, 256, 0, stream>>>(l2w, WThi + OL2, WTlo + OL2, 1024, 256);

    if (full) {
        float* qb  = base;                  // [0,1MC): q, then o, then x2
        float* x2  = base;
        float* kvb = base + MC;             // [1MC,3MC): kv; later hb/hc
        float* hbB = base + MC;
        float* hcB = base + 2 * MC;

        mgemm_kernel<EPI_NONE><<<dim3(2, TOK / 128), 256, 0, stream>>>(
            win, WThi + OQ, WTlo + OQ, bq, qb, nullptr, TOK, CDIM, CDIM);
        mgemm_kernel<EPI_NONE><<<dim3(4, TOK / 128), 256, 0, stream>>>(
            win, WThi + OKV, WTlo + OKV, bkv, kvb, nullptr, TOK, 2 * CDIM, CDIM);
        attn_kernel<<<(TOK / 64) * 8, 64, 0, stream>>>(qb, kvb, rpb);
        mgemm_kernel<EPI_WINRES><<<dim3(2, TOK / 128), 256, 0, stream>>>(
            qb, WThi + OP, WTlo + OP, pb, x1, x, TOK, CDIM, CDIM);
        ln_kernel<false><<<TOK / 4, 256, 0, stream>>>(x1, n2w, n2b, x2);
        for (int b = 0; b < 4; ++b) {
            const float* x2b = x2 + (size_t)b * BC;
            const float* x1b = x1 + (size_t)b * BC;
            float* outb = out + (size_t)b * BC;
            mgemm_kernel<EPI_GELU><<<dim3(8, PIXB / 128), 256, 0, stream>>>(
                x2b, WThi + OL1, WTlo + OL1, l1b, hbB, nullptr, PIXB, HIDD, CDIM);
            dwconv_kernel<<<PIXB * (HIDD / 4) / 256, 256, 0, stream>>>(
                hbB, wT, dwb, hcB, 0);
            mgemm_kernel<EPI_RES><<<dim3(2, PIXB / 128), 256, 0, stream>>>(
                hcB, WThi + OL2, WTlo + OL2, l2b, outb, x1b, PIXB, CDIM, HIDD);
        }
    } else {
        // SPLIT path: peak ~1.5*MC + 1M floats.
        float* qb_s  = base;
        float* kvb_s = base + MC / 4;
        for (int b = 0; b < 4; ++b) {
            const float* winb = win + (size_t)b * BC;
            const float* xb   = x   + (size_t)b * BC;
            float* x1b = x1 + (size_t)b * BC;
            mgemm_kernel<EPI_NONE><<<dim3(2, PIXB / 128), 256, 0, stream>>>(
                winb, WThi + OQ, WTlo + OQ, bq, qb_s, nullptr, PIXB, CDIM, CDIM);
            mgemm_kernel<EPI_NONE><<<dim3(4, PIXB / 128), 256, 0, stream>>>(
                winb, WThi + OKV, WTlo + OKV, bkv, kvb_s, nullptr, PIXB, 2 * CDIM, CDIM);
            attn_kernel<<<(PIXB / 64) * 8, 64, 0, stream>>>(qb_s, kvb_s, rpb);
            mgemm_kernel<EPI_WINRES><<<dim3(2, PIXB / 128), 256, 0, stream>>>(
                qb_s, WThi + OP, WTlo + OP, pb, x1b, xb, PIXB, CDIM, CDIM);
        }
        float* x2_s = base;
        float* hb_s = base + MC / 4;
        float* hc_s = base + MC / 4 + MC;
        const int SROWS = 32, SPIX = SROWS * 128;
        for (int b = 0; b < 4; ++b) {
            const float* x1b = x1 + (size_t)b * BC;
            float* outb = out + (size_t)b * BC;
            ln_kernel<false><<<PIXB / 4, 256, 0, stream>>>(x1b, n2w, n2b, x2_s);
            mgemm_kernel<EPI_GELU><<<dim3(8, PIXB / 128), 256, 0, stream>>>(
                x2_s, WThi + OL1, WTlo + OL1, l1b, hb_s, nullptr, PIXB, HIDD, CDIM);
            for (int s = 0; s < 4; ++s) {
                dwconv_kernel<<<SPIX * (HIDD / 4) / 256, 256, 0, stream>>>(
                    hb_s, wT, dwb, hc_s, s * SROWS);
                mgemm_kernel<EPI_RES><<<dim3(2, SPIX / 128), 256, 0, stream>>>(
                    hc_s, WThi + OL2, WTlo + OL2, l2b,
                    outb + (size_t)s * SPIX * CDIM,
                    x1b + (size_t)s * SPIX * CDIM, SPIX, CDIM, HIDD);
            }
        }
    }
}

// Round 9
// 1134.809 us; speedup vs baseline: 1.6154x; 1.0216x over previous
//
#include <hip/hip_runtime.h>
#include <math.h>

// Swin transformer block. GEMMs on MFMA with 2-term bf16 splits
// (Ah*Bh + Ah*Bl + Al*Bh); activations pre-split by producers so the GEMM
// K-loop has zero convert VALU. Attention: fp32 VALU, online softmax.
// B=4, H=W=128, C=256, HID=1024, HEADS=8, hd=32, WIN=8, SHIFT=4.
//
// Workspace (floats): [0,9216) dwconv wT | [16384,802816) weight splits |
// [802816,835584) bias8T | base=ws+1048576: q/kv/x2/hb/hc slots (3*MC).
// Total = 1048576 + 3*MC floats — R6 ran this footprint successfully.
// d_out holds win hi/lo pair, then x1 fp32, then the final output.

#define TOK   65536
#define CDIM  256
#define HIDD  1024
#define PIXB  16384

typedef __attribute__((ext_vector_type(8))) short bf16x8;
typedef __attribute__((ext_vector_type(4))) short s16x4;
typedef __attribute__((ext_vector_type(4))) float f32x4;

__device__ __forceinline__ float gelu_exact(float v) {
    return 0.5f * v * (1.0f + erff(v * 0.7071067811865476f));
}
__device__ __forceinline__ unsigned short bf16_rne(float f) {
    unsigned u = __float_as_uint(f);
    unsigned r = u + 0x7fffu + ((u >> 16) & 1u);
    return (unsigned short)(r >> 16);
}
__device__ __forceinline__ float bf16_f(short s) {
    return __uint_as_float(((unsigned)(unsigned short)s) << 16);
}
struct HL { short h, l; };
__device__ __forceinline__ HL split2(float f) {
    HL r;
    unsigned short uh = bf16_rne(f);
    r.h = (short)uh;
    r.l = (short)bf16_rne(f - __uint_as_float((unsigned)uh << 16));
    return r;
}

// window-layout token t -> spatial row (b*16384 + h*128 + w), incl. unshift.
__device__ __forceinline__ int win_row_map(int t) {
    int bw = t >> 6, n = t & 63;
    int b = bw >> 8, widx = bw & 255;
    int wh = widx >> 4, ww = widx & 15;
    int i = n >> 3, j = n & 7;
    int h = (wh * 8 + i + 4) & 127;
    int w = (ww * 8 + j + 4) & 127;
    return (b << 14) | (h << 7) | w;
}

// -------- LayerNorm: fp32 in -> bf16 hi/lo pair out (1 wave / token) -------
template<bool WINDOW>
__global__ __launch_bounds__(256) void ln_kernel(const float* __restrict__ in,
    const float* __restrict__ gw, const float* __restrict__ gb,
    short* __restrict__ oh, short* __restrict__ ol)
{
    int wave = threadIdx.x >> 6;
    int lane = threadIdx.x & 63;
    int t = blockIdx.x * 4 + wave;
    int src = WINDOW ? win_row_map(t) : t;
    const float4 v = *(const float4*)(in + (size_t)src * CDIM + lane * 4);
    float sum = v.x + v.y + v.z + v.w;
    float sq  = v.x * v.x + v.y * v.y + v.z * v.z + v.w * v.w;
#pragma unroll
    for (int off = 32; off > 0; off >>= 1) {
        sum += __shfl_xor(sum, off);
        sq  += __shfl_xor(sq, off);
    }
    float mean = sum * (1.0f / CDIM);
    float var  = sq * (1.0f / CDIM) - mean * mean;
    float rstd = rsqrtf(var + 1e-5f);
    const float4 w4 = *(const float4*)(gw + lane * 4);
    const float4 b4 = *(const float4*)(gb + lane * 4);
    float o0 = (v.x - mean) * rstd * w4.x + b4.x;
    float o1 = (v.y - mean) * rstd * w4.y + b4.y;
    float o2 = (v.z - mean) * rstd * w4.z + b4.z;
    float o3 = (v.w - mean) * rstd * w4.w + b4.w;
    s16x4 vh, vl;
    HL r0 = split2(o0); vh[0] = r0.h; vl[0] = r0.l;
    HL r1 = split2(o1); vh[1] = r1.h; vl[1] = r1.l;
    HL r2 = split2(o2); vh[2] = r2.h; vl[2] = r2.l;
    HL r3 = split2(o3); vh[3] = r3.h; vl[3] = r3.l;
    size_t o = (size_t)t * CDIM + lane * 4;
    *(s16x4*)(oh + o) = vh;
    *(s16x4*)(ol + o) = vl;
}

// ------- weight prep: W[K][N] fp32 -> hi/lo bf16 in [N][K] layout ----------
__global__ __launch_bounds__(256) void wprep_kernel(const float* __restrict__ W,
    short* __restrict__ hi, short* __restrict__ lo, int K, int N)
{
    int idx = blockIdx.x * 256 + threadIdx.x;
    if (idx >= K * N) return;
    int k = idx / N, n = idx - k * N;
    HL r = split2(W[idx]);
    hi[(size_t)n * K + k] = r.h;
    lo[(size_t)n * K + k] = r.l;
}

// ------- bias prep: rpb -> bias8T[head][key][query] (transposed) -----------
__global__ __launch_bounds__(256) void bias_prep_kernel(
    const float* __restrict__ rpb, float* __restrict__ bias8T)
{
    int gid = blockIdx.x * 256 + threadIdx.x;
    if (gid >= 8 * 64 * 64) return;
    int h = gid >> 12, m = (gid >> 6) & 63, q = gid & 63;
    int qi = q >> 3, qj = q & 7, mi = m >> 3, mj = m & 7;
    int ridx = (qi - mi + 7) * 15 + (qj - mj + 7);
    bias8T[gid] = rpb[ridx * 8 + h];
}

// ---------------- MFMA GEMM, 128x128 tile, 256 threads (4 waves) -----------
// A pre-split bf16 planes [M][K]; B pre-split [N][K]. 48 MFMA + 16 ds_read
// per k-step of 32 per wave; register-prefetch of next tile under MFMA.
#define EPI_PAIR   0   // write bf16 hi/lo pair (q, kv)
#define EPI_GELU   1   // fp32 + GELU (lin1)
#define EPI_WINRES 2   // fp32, out[map(row)] = R[map(row)] + v (proj)
#define EPI_RES    3   // fp32, out[row] = R[row] + v (lin2; in-place safe)

template<int EPI>
__global__ __launch_bounds__(256) void mgemm_kernel(
    const short* __restrict__ Agh, const short* __restrict__ Agl,
    const short* __restrict__ BTh, const short* __restrict__ BTl,
    const float* __restrict__ bias,
    float* __restrict__ C, const float* __restrict__ R,
    short* __restrict__ Ch, short* __restrict__ Cl,
    int M, int N, int K)
{
    __shared__ short lds[4 * 5120];
    short* Ah = lds;
    short* Al = lds + 5120;
    short* Bh = lds + 10240;
    short* Bl = lds + 15360;

    const int tid = threadIdx.x;
    const int bm = blockIdx.y << 7, bn = blockIdx.x << 7;
    const int sr = tid >> 1;            // staging row (0..127)
    const int sc = (tid & 1) << 4;      // staging k offset (0/16)

    const short* pAh = Agh + (size_t)(bm + sr) * K + sc;
    const short* pAl = Agl + (size_t)(bm + sr) * K + sc;
    const short* pBh = BTh + (size_t)(bn + sr) * K + sc;
    const short* pBl = BTl + (size_t)(bn + sr) * K + sc;

    const int wid = tid >> 6, lane = tid & 63;
    const int wr = wid >> 1, wc = wid & 1;
    const int lr = lane & 15, lkq = lane >> 4;
    const int lk = lkq << 3;

    f32x4 acc[4][4] = {};

    bf16x8 rah0 = *(const bf16x8*)(pAh);
    bf16x8 rah1 = *(const bf16x8*)(pAh + 8);
    bf16x8 ral0 = *(const bf16x8*)(pAl);
    bf16x8 ral1 = *(const bf16x8*)(pAl + 8);
    bf16x8 rbh0 = *(const bf16x8*)(pBh);
    bf16x8 rbh1 = *(const bf16x8*)(pBh + 8);
    bf16x8 rbl0 = *(const bf16x8*)(pBl);
    bf16x8 rbl1 = *(const bf16x8*)(pBl + 8);

    for (int k0 = 0; k0 < K; k0 += 32) {
        __syncthreads();   // prior iteration's LDS reads complete
        *(bf16x8*)&Ah[sr * 40 + sc]     = rah0;
        *(bf16x8*)&Ah[sr * 40 + sc + 8] = rah1;
        *(bf16x8*)&Al[sr * 40 + sc]     = ral0;
        *(bf16x8*)&Al[sr * 40 + sc + 8] = ral1;
        *(bf16x8*)&Bh[sr * 40 + sc]     = rbh0;
        *(bf16x8*)&Bh[sr * 40 + sc + 8] = rbh1;
        *(bf16x8*)&Bl[sr * 40 + sc]     = rbl0;
        *(bf16x8*)&Bl[sr * 40 + sc + 8] = rbl1;
        __syncthreads();   // tile ready
        if (k0 + 32 < K) { // prefetch next tile under the MFMAs
            rah0 = *(const bf16x8*)(pAh + k0 + 32);
            rah1 = *(const bf16x8*)(pAh + k0 + 40);
            ral0 = *(const bf16x8*)(pAl + k0 + 32);
            ral1 = *(const bf16x8*)(pAl + k0 + 40);
            rbh0 = *(const bf16x8*)(pBh + k0 + 32);
            rbh1 = *(const bf16x8*)(pBh + k0 + 40);
            rbl0 = *(const bf16x8*)(pBl + k0 + 32);
            rbl1 = *(const bf16x8*)(pBl + k0 + 40);
        }

        bf16x8 fah[4], fal[4], fbh[4], fbl[4];
#pragma unroll
        for (int mi = 0; mi < 4; ++mi) {
            int off = (wr * 64 + mi * 16 + lr) * 40 + lk;
            fah[mi] = *(const bf16x8*)&Ah[off];
            fal[mi] = *(const bf16x8*)&Al[off];
        }
#pragma unroll
        for (int ni = 0; ni < 4; ++ni) {
            int off = (wc * 64 + ni * 16 + lr) * 40 + lk;
            fbh[ni] = *(const bf16x8*)&Bh[off];
            fbl[ni] = *(const bf16x8*)&Bl[off];
        }
#pragma unroll
        for (int mi = 0; mi < 4; ++mi)
#pragma unroll
            for (int ni = 0; ni < 4; ++ni) {
                acc[mi][ni] = __builtin_amdgcn_mfma_f32_16x16x32_bf16(
                    fah[mi], fbh[ni], acc[mi][ni], 0, 0, 0);
                acc[mi][ni] = __builtin_amdgcn_mfma_f32_16x16x32_bf16(
                    fah[mi], fbl[ni], acc[mi][ni], 0, 0, 0);
                acc[mi][ni] = __builtin_amdgcn_mfma_f32_16x16x32_bf16(
                    fal[mi], fbh[ni], acc[mi][ni], 0, 0, 0);
            }
    }

    // epilogue: D frag mapping col = lane&15, row = (lane>>4)*4 + reg
#pragma unroll
    for (int mi = 0; mi < 4; ++mi) {
#pragma unroll
        for (int ni = 0; ni < 4; ++ni) {
            int col = bn + wc * 64 + ni * 16 + lr;
            float bv = bias[col];
#pragma unroll
            for (int r = 0; r < 4; ++r) {
                int row = bm + wr * 64 + mi * 16 + lkq * 4 + r;
                float v = acc[mi][ni][r] + bv;
                if (EPI == EPI_GELU) v = gelu_exact(v);
                int drow = (EPI == EPI_WINRES) ? win_row_map(row) : row;
                if (EPI == EPI_WINRES || EPI == EPI_RES)
                    v += R[(size_t)drow * N + col];
                if (EPI == EPI_PAIR) {
                    HL s = split2(v);
                    Ch[(size_t)row * N + col] = s.h;
                    Cl[(size_t)row * N + col] = s.l;
                } else {
                    C[(size_t)drow * N + col] = v;
                }
            }
        }
    }
}

// ------- Windowed attention: 1 wave / (window, head), online softmax -------
// Reads q/kv bf16 pairs, writes o bf16 pair in place over q (disjoint
// per-(token, head-slice)). No s[64] array -> no scratch spills.
// Shift-mask fast path: only windows with wh==15 or ww==15 straddle region
// boundaries (225/256 windows skip label math entirely; wave-uniform).
__global__ __launch_bounds__(64) void attn_kernel(
    short* __restrict__ qh, short* __restrict__ ql,
    const short* __restrict__ kvh, const short* __restrict__ kvl,
    const float* __restrict__ bias8T)
{
    __shared__ float kS[64][33];
    __shared__ float vS[64][33];
    int blk = blockIdx.x;
    int bw = blk >> 3, head = blk & 7;
    int lane = threadIdx.x;

    // stage K/V (reconstructed fp32), lane = token
    size_t ekv = ((size_t)(bw * 64 + lane)) * 512 + head * 32;
#pragma unroll
    for (int j = 0; j < 4; ++j) {
        bf16x8 h8 = *(const bf16x8*)(kvh + ekv + j * 8);
        bf16x8 l8 = *(const bf16x8*)(kvl + ekv + j * 8);
#pragma unroll
        for (int e = 0; e < 8; ++e)
            kS[lane][j * 8 + e] = bf16_f(h8[e]) + bf16_f(l8[e]);
        bf16x8 hv = *(const bf16x8*)(kvh + ekv + 256 + j * 8);
        bf16x8 lv = *(const bf16x8*)(kvl + ekv + 256 + j * 8);
#pragma unroll
        for (int e = 0; e < 8; ++e)
            vS[lane][j * 8 + e] = bf16_f(hv[e]) + bf16_f(lv[e]);
    }
    // q slice into registers
    float qr[32];
    size_t eq = ((size_t)(bw * 64 + lane)) * 256 + head * 32;
#pragma unroll
    for (int j = 0; j < 4; ++j) {
        bf16x8 h8 = *(const bf16x8*)(qh + eq + j * 8);
        bf16x8 l8 = *(const bf16x8*)(ql + eq + j * 8);
#pragma unroll
        for (int e = 0; e < 8; ++e)
            qr[j * 8 + e] = bf16_f(h8[e]) + bf16_f(l8[e]);
    }
    __syncthreads();

    int widx = bw & 255;
    int wh = widx >> 4, ww = widx & 15;
    const bool boundary = (wh == 15) || (ww == 15);  // wave-uniform
    int i1 = lane >> 3, j1 = lane & 7;
    int h1 = wh * 8 + i1, w1 = ww * 8 + j1;
    int lbl1 = (h1 < 120 ? 0 : (h1 < 124 ? 1 : 2)) * 3
             + (w1 < 120 ? 0 : (w1 < 124 ? 1 : 2));
    const float scale = 0.17677669529663687f;  // 32^-0.5
    const float* bT = bias8T + head * 4096;

    float mx = -1e30f, sum = 0.f;
    float oa[32];
#pragma unroll
    for (int d = 0; d < 32; ++d) oa[d] = 0.f;

    for (int m = 0; m < 64; ++m) {
        float a = 0.f;
#pragma unroll
        for (int d = 0; d < 32; ++d) a = fmaf(qr[d], kS[m][d], a);
        float sv = a * scale + bT[m * 64 + lane];   // coalesced, L1-hot
        if (boundary) {
            int i2 = m >> 3, j2 = m & 7;
            int h2 = wh * 8 + i2, w2 = ww * 8 + j2;
            int lbl2 = (h2 < 120 ? 0 : (h2 < 124 ? 1 : 2)) * 3
                     + (w2 < 120 ? 0 : (w2 < 124 ? 1 : 2));
            if (lbl1 != lbl2) sv -= 100.f;
        }
        if (sv > mx) {
            float r = __expf(mx - sv);
            sum *= r;
#pragma unroll
            for (int d = 0; d < 32; ++d) oa[d] *= r;
            mx = sv;
        }
        float e = __expf(sv - mx);
        sum += e;
#pragma unroll
        for (int d = 0; d < 32; ++d) oa[d] = fmaf(e, vS[m][d], oa[d]);
    }

    float inv = 1.0f / sum;
#pragma unroll
    for (int j = 0; j < 4; ++j) {
        bf16x8 vh, vl;
#pragma unroll
        for (int e = 0; e < 8; ++e) {
            HL s = split2(oa[j * 8 + e] * inv);
            vh[e] = s.h; vl[e] = s.l;
        }
        *(bf16x8*)(qh + eq + j * 8) = vh;   // in place over q
        *(bf16x8*)(ql + eq + j * 8) = vl;
    }
}

// ---------------- depthwise-conv weight transpose: [HID,3,3]->[9][HID] -----
__global__ __launch_bounds__(256) void prep_dw_kernel(const float* __restrict__ dww,
    float* __restrict__ wT)
{
    int gid = blockIdx.x * 256 + threadIdx.x;
    if (gid >= 9 * HIDD) return;
    int k = gid >> 10, c = gid & 1023;
    wT[gid] = dww[c * 9 + k];
}

// --- depthwise 3x3 conv + bias + GELU -> bf16 pair, one batch image --------
__global__ __launch_bounds__(256) void dwconv_kernel(const float* __restrict__ h,
    const float* __restrict__ wT, const float* __restrict__ db,
    short* __restrict__ oh, short* __restrict__ ol)
{
    int gid = blockIdx.x * 256 + threadIdx.x;   // PIXB*HIDD/4 threads
    int c = (gid & 255) << 2;                   // channel (x4)
    int pix = gid >> 8;                         // y*128 + x (batch-local)
    int x = pix & 127, y = pix >> 7;

    float4 acc = *(const float4*)(db + c);
#pragma unroll
    for (int ky = 0; ky < 3; ++ky) {
        int yy = y + ky - 1;
        if (yy < 0 || yy > 127) continue;
#pragma unroll
        for (int kx = 0; kx < 3; ++kx) {
            int xx = x + kx - 1;
            if (xx < 0 || xx > 127) continue;
            float4 iv = *(const float4*)(h + ((size_t)((yy << 7) | xx) << 10) + c);
            float4 wv = *(const float4*)(wT + (ky * 3 + kx) * HIDD + c);
            acc.x = fmaf(iv.x, wv.x, acc.x);
            acc.y = fmaf(iv.y, wv.y, acc.y);
            acc.z = fmaf(iv.z, wv.z, acc.z);
            acc.w = fmaf(iv.w, wv.w, acc.w);
        }
    }
    s16x4 vh, vl;
    HL r0 = split2(gelu_exact(acc.x)); vh[0] = r0.h; vl[0] = r0.l;
    HL r1 = split2(gelu_exact(acc.y)); vh[1] = r1.h; vl[1] = r1.l;
    HL r2 = split2(gelu_exact(acc.z)); vh[2] = r2.h; vl[2] = r2.l;
    HL r3 = split2(gelu_exact(acc.w)); vh[3] = r3.h; vl[3] = r3.l;
    size_t o = ((size_t)pix << 10) + c;
    *(s16x4*)(oh + o) = vh;
    *(s16x4*)(ol + o) = vl;
}

// ---------------------------------------------------------------------------
extern "C" void kernel_launch(void* const* d_in, const int* in_sizes, int n_in,
                              void* d_out, int out_size, void* d_ws, size_t ws_size,
                              hipStream_t stream) {
    const float* x    = (const float*)d_in[0];
    const float* n1w  = (const float*)d_in[3];
    const float* n1b  = (const float*)d_in[4];
    const float* wq   = (const float*)d_in[5];
    const float* bq   = (const float*)d_in[6];
    const float* wkv  = (const float*)d_in[7];
    const float* bkv  = (const float*)d_in[8];
    const float* rpb  = (const float*)d_in[9];
    const float* pw   = (const float*)d_in[10];
    const float* pb   = (const float*)d_in[11];
    const float* n2w  = (const float*)d_in[12];
    const float* n2b  = (const float*)d_in[13];
    const float* l1w  = (const float*)d_in[14];
    const float* l1b  = (const float*)d_in[15];
    const float* dww  = (const float*)d_in[16];
    const float* dwb  = (const float*)d_in[17];
    const float* l2w  = (const float*)d_in[18];
    const float* l2b  = (const float*)d_in[19];
    float* out = (float*)d_out;
    float* ws  = (float*)d_ws;

    const size_t MC = (size_t)TOK * CDIM;   // 16,777,216
    const size_t BC = (size_t)PIXB * CDIM;  // per-batch fp32 row block

    float* wT     = ws;                       // [0, 9216)
    short* WThi   = (short*)(ws + 16384);     // 786432 shorts
    short* WTlo   = (short*)(ws + 16384 + 393216);
    float* bias8T = ws + 802816;              // 32768 floats
    float* base   = ws + 1048576;

    short* sbase = (short*)base;
    short* qh  = sbase;            // q pair -> o pair (in place)
    short* ql  = sbase + MC;
    short* x2h = sbase;            // x2 pair reuses q slot after proj
    short* x2l = sbase + MC;
    short* kvh = sbase + 2 * MC;   // kv pair
    short* kvl = sbase + 4 * MC;
    float* hb  = base + MC;        // per-batch lin1 out (kv slot, dead)
    short* hch = (short*)(base + 2 * MC);  // per-batch conv pair
    short* hcl = hch + MC;

    short* winh = (short*)out;     // d_out: win pair, then x1 fp32, then out
    short* winl = winh + MC;
    float* x1   = out;

    // weight-split offsets (shorts): [wq, wkv, pw, l1w, l2w]
    const size_t OQ = 0, OKV = 65536, OP = 196608, OL1 = 262144, OL2 = 524288;

    // prep
    ln_kernel<true><<<TOK / 4, 256, 0, stream>>>(x, n1w, n1b, winh, winl);
    prep_dw_kernel<<<(9 * HIDD + 255) / 256, 256, 0, stream>>>(dww, wT);
    bias_prep_kernel<<<(8 * 64 * 64) / 256, 256, 0, stream>>>(rpb, bias8T);
    wprep_kernel<<<(256 * 256 + 255) / 256, 256, 0, stream>>>(wq,  WThi + OQ,  WTlo + OQ,  256, 256);
    wprep_kernel<<<(256 * 512 + 255) / 256, 256, 0, stream>>>(wkv, WThi + OKV, WTlo + OKV, 256, 512);
    wprep_kernel<<<(256 * 256 + 255) / 256, 256, 0, stream>>>(pw,  WThi + OP,  WTlo + OP,  256, 256);
    wprep_kernel<<<(256 * 1024 + 255) / 256, 256, 0, stream>>>(l1w, WThi + OL1, WTlo + OL1, 256, 1024);
    wprep_kernel<<<(1024 * 256 + 255) / 256, 256, 0, stream>>>(l2w, WThi + OL2, WTlo + OL2, 1024, 256);

    // q / kv projections -> bf16 pairs
    mgemm_kernel<EPI_PAIR><<<dim3(2, TOK / 128), 256, 0, stream>>>(
        winh, winl, WThi + OQ, WTlo + OQ, bq, nullptr, nullptr, qh, ql,
        TOK, CDIM, CDIM);
    mgemm_kernel<EPI_PAIR><<<dim3(4, TOK / 128), 256, 0, stream>>>(
        winh, winl, WThi + OKV, WTlo + OKV, bkv, nullptr, nullptr, kvh, kvl,
        TOK, 2 * CDIM, CDIM);
    // attention (o pair over q pair)
    attn_kernel<<<(TOK / 64) * 8, 64, 0, stream>>>(qh, ql, kvh, kvl, bias8T);
    // proj + window-reverse + unshift + residual -> x1 fp32 (d_out)
    mgemm_kernel<EPI_WINRES><<<dim3(2, TOK / 128), 256, 0, stream>>>(
        qh, ql, WThi + OP, WTlo + OP, pb, x1, x, nullptr, nullptr,
        TOK, CDIM, CDIM);
    // LN2 -> x2 pair
    ln_kernel<false><<<TOK / 4, 256, 0, stream>>>(x1, n2w, n2b, x2h, x2l);
    // MLP per batch image
    for (int b = 0; b < 4; ++b) {
        const short* x2hb = x2h + (size_t)b * BC;
        const short* x2lb = x2l + (size_t)b * BC;
        const float* x1b  = x1 + (size_t)b * BC;
        float* outb = out + (size_t)b * BC;
        mgemm_kernel<EPI_GELU><<<dim3(8, PIXB / 128), 256, 0, stream>>>(
            (const short*)x2hb, (const short*)x2lb, WThi + OL1, WTlo + OL1,
            l1b, hb, nullptr, nullptr, nullptr, PIXB, HIDD, CDIM);
        dwconv_kernel<<<PIXB * (HIDD / 4) / 256, 256, 0, stream>>>(
            hb, wT, dwb, hch, hcl);
        mgemm_kernel<EPI_RES><<<dim3(2, PIXB / 128), 256, 0, stream>>>(
            hch, hcl, WThi + OL2, WTlo + OL2, l2b, outb, x1b, nullptr, nullptr,
            PIXB, CDIM, HIDD);
    }
}